// Round 1
// baseline (449.543 us; speedup 1.0000x reference)
//
#include <hip/hip_runtime.h>
#include <math.h>

#define TOK 16384
#define DD  2048
#define EE  64
#define BM  32
#define BK  32
#define NC  128          // 64 gate cols + 64 noise cols
#define XS_S 36          // BM+4 : keeps ds_read_b128 16B-aligned, conflicts <=2-way
#define WT_S 132         // NC+4

__global__ __launch_bounds__(256, 2)
void gating_kernel(const float* __restrict__ x, const float* __restrict__ rn,
                   const float* __restrict__ Wg, const float* __restrict__ bg,
                   const float* __restrict__ Wn, float* __restrict__ out,
                   float* __restrict__ cnt_g, float* __restrict__ psum_g) {
  __shared__ float xs[BK * XS_S];
  __shared__ float wt[BK * WT_S];
  __shared__ float Lb[BM][NC + 4];   // logits tile (gate | noise)
  __shared__ float Pb[BM][EE + 1];   // exp(noisy) per token
  __shared__ float Sb[BM * EE];      // sparse output tile
  __shared__ float isum[BM];
  __shared__ int   ti[BM][2];

  const int t  = threadIdx.x;
  const int t0 = blockIdx.x * BM;

  const int tm = t >> 5, tn = t & 31;
  const int m0 = tm << 2, n0 = tn << 2;   // 8 m-groups x 32 n-groups = 32x128

  const int xm = t >> 3;                  // 0..31 token row for x staging
  const int xk = (t & 7) << 2;            // 0..28 k offset (float4)

  float acc[4][4];
#pragma unroll
  for (int r = 0; r < 4; ++r)
#pragma unroll
    for (int c = 0; c < 4; ++c) acc[r][c] = 0.f;

  for (int kc = 0; kc < DD; kc += BK) {
    // stage x tile: 32 tokens x 32 k (coalesced 128B per 8 lanes)
    {
      const float4 v = *reinterpret_cast<const float4*>(
          x + (size_t)(t0 + xm) * DD + kc + xk);
      xs[(xk + 0) * XS_S + xm] = v.x;
      xs[(xk + 1) * XS_S + xm] = v.y;
      xs[(xk + 2) * XS_S + xm] = v.z;
      xs[(xk + 3) * XS_S + xm] = v.w;
    }
    // stage W tile: 128 cols x 32 k
#pragma unroll
    for (int i = 0; i < 4; ++i) {
      const int q = t + 256 * i;
      const int e = q >> 3;
      const int k = (q & 7) << 2;
      const float* src = (e < EE) ? (Wg + (size_t)e * DD)
                                  : (Wn + (size_t)(e - EE) * DD);
      const float4 v = *reinterpret_cast<const float4*>(src + kc + k);
      wt[(k + 0) * WT_S + e] = v.x;
      wt[(k + 1) * WT_S + e] = v.y;
      wt[(k + 2) * WT_S + e] = v.z;
      wt[(k + 3) * WT_S + e] = v.w;
    }
    __syncthreads();
#pragma unroll
    for (int k = 0; k < BK; ++k) {
      const float4 a = *reinterpret_cast<const float4*>(&xs[k * XS_S + m0]);
      const float4 b = *reinterpret_cast<const float4*>(&wt[k * WT_S + n0]);
      float av[4] = {a.x, a.y, a.z, a.w};
      float bv[4] = {b.x, b.y, b.z, b.w};
#pragma unroll
      for (int r = 0; r < 4; ++r)
#pragma unroll
        for (int c = 0; c < 4; ++c)
          acc[r][c] = fmaf(av[r], bv[c], acc[r][c]);
    }
    __syncthreads();
  }

  // ---- epilogue ----
#pragma unroll
  for (int r = 0; r < 4; ++r) {
    float4 v = make_float4(acc[r][0], acc[r][1], acc[r][2], acc[r][3]);
    *reinterpret_cast<float4*>(&Lb[m0 + r][n0]) = v;
  }
#pragma unroll
  for (int i = 0; i < 8; ++i) Sb[t + 256 * i] = 0.f;
  __syncthreads();

  if (t < BM) {
    const int tok = t0 + t;
    float v1 = -1e30f, v2 = -1e30f;
    int   i1 = 0, i2 = 0;
    float s = 0.f;
    for (int e = 0; e < EE; ++e) {
      float g  = Lb[t][e] + bg[e];
      float h  = Lb[t][EE + e];
      float sp = (h > 20.f) ? h : log1pf(expf(h));
      float v  = g + rn[(size_t)tok * EE + e] * (sp + 0.01f);
      float ev = expf(v);
      s += ev;
      Pb[t][e] = ev;
      if (v > v1)      { v2 = v1; i2 = i1; v1 = v; i1 = e; }
      else if (v > v2) { v2 = v;  i2 = e; }
    }
    isum[t] = 1.f / s;
    ti[t][0] = i1; ti[t][1] = i2;
    // softmax over the top-2, max-subtracted like the reference
    float e2 = expf(v2 - v1);
    float dn = 1.f + e2;
    Sb[t * EE + i1] = 1.f / dn;
    Sb[t * EE + i2] = e2 / dn;
  }
  __syncthreads();

  // coalesced sparse write: 32 tokens x 64 experts = 2048 floats
#pragma unroll
  for (int i = 0; i < 8; ++i)
    out[(size_t)t0 * EE + t + 256 * i] = Sb[t + 256 * i];

  // per-block aux partials -> global atomics (64 experts)
  if (t < EE) {
    float s = 0.f;
    int   c = 0;
#pragma unroll
    for (int m = 0; m < BM; ++m) {
      s += Pb[m][t] * isum[m];
      c += (ti[m][0] == t) + (ti[m][1] == t);
    }
    atomicAdd(&psum_g[t], s);
    atomicAdd(&cnt_g[t], (float)c);
  }
}

__global__ void aux_kernel(const float* __restrict__ cnt_g,
                           const float* __restrict__ psum_g,
                           float* __restrict__ out) {
  int e = threadIdx.x;  // 64 lanes, one wave
  float v = cnt_g[e] * psum_g[e];
#pragma unroll
  for (int o = 32; o > 0; o >>= 1) v += __shfl_down(v, o);
  if (e == 0)
    out[(size_t)TOK * EE] = v * ((float)EE / ((float)TOK * (float)TOK));
}

extern "C" void kernel_launch(void* const* d_in, const int* in_sizes, int n_in,
                              void* d_out, int out_size, void* d_ws, size_t ws_size,
                              hipStream_t stream) {
  const float* x  = (const float*)d_in[0];
  const float* rn = (const float*)d_in[1];
  const float* Wg = (const float*)d_in[2];
  const float* bg = (const float*)d_in[3];
  const float* Wn = (const float*)d_in[4];
  float* out    = (float*)d_out;
  float* cnt_g  = (float*)d_ws;
  float* psum_g = cnt_g + EE;

  hipMemsetAsync(d_ws, 0, 2 * EE * sizeof(float), stream);
  gating_kernel<<<TOK / BM, 256, 0, stream>>>(x, rn, Wg, bg, Wn, out, cnt_g, psum_g);
  aux_kernel<<<1, 64, 0, stream>>>(cnt_g, psum_g, out);
}

// Round 2
// 249.399 us; speedup vs baseline: 1.8025x; 1.8025x over previous
//
#include <hip/hip_runtime.h>
#include <math.h>

#define TOK 16384
#define DD  2048
#define EE  64
#define MT  64           // tokens per block
#define BKC 32           // k per chunk
#define NKC 64           // DD / BKC
#define LDA 40           // halves per token row in LDS (80B stride: 16B-aligned, <=2-way conflicts)

typedef _Float16 half8 __attribute__((ext_vector_type(8)));
typedef float floatx4 __attribute__((ext_vector_type(4)));

// ---- W pre-split: f32 -> (hi,lo) f16, frag-major layout ----
// Wf[ct][kc][s][lane][8] halves; ct 0..3 = gate col-tiles, 4..7 = noise col-tiles.
// lane l of a wave maps to col = ct*16 + (l&15), k = kc*32 + (l>>4)*8 + j.
__global__ void build_wf(const float* __restrict__ Wg, const float* __restrict__ Wn,
                         _Float16* __restrict__ wf) {
  int tid  = blockIdx.x * 256 + threadIdx.x;   // 8*64*64 = 32768 threads
  int lane = tid & 63;
  int kc   = (tid >> 6) & 63;
  int ct   = tid >> 12;                        // 0..7
  int col  = (ct & 3) * 16 + (lane & 15);
  int k    = kc * 32 + (lane >> 4) * 8;
  const float* W = (ct < 4) ? Wg : Wn;
  const float* src = W + (size_t)col * DD + k;
  float4 a = *reinterpret_cast<const float4*>(src);
  float4 b = *reinterpret_cast<const float4*>(src + 4);
  float v[8] = {a.x, a.y, a.z, a.w, b.x, b.y, b.z, b.w};
  half8 hi, lo;
#pragma unroll
  for (int j = 0; j < 8; ++j) {
    _Float16 h = (_Float16)v[j];
    hi[j] = h;
    lo[j] = (_Float16)(v[j] - (float)h);
  }
  size_t base = (((size_t)(ct * 64 + kc) * 2 + 0) * 64 + lane) * 8;
  *reinterpret_cast<half8*>(wf + base)       = hi;
  *reinterpret_cast<half8*>(wf + base + 512) = lo;   // s=1 plane is +64*8 halves
}

__global__ __launch_bounds__(256, 1)
void gating_kernel(const float* __restrict__ x, const float* __restrict__ rn,
                   const _Float16* __restrict__ wf, const float* __restrict__ bg,
                   float* __restrict__ out,
                   float* __restrict__ cnt_g, float* __restrict__ psum_g) {
  __shared__ _Float16 xs[2][2][MT * LDA];   // [buf][split][token*LDA + k]
  __shared__ float Lb[MT][129];             // logits (gate 0..63 | noise 64..127)
  __shared__ float Pb[MT][65];              // exp(noisy)
  __shared__ float Rb[MT][65];              // raw_noise tile
  __shared__ float Sb[MT * EE];             // sparse out tile
  __shared__ float Bgs[EE];
  __shared__ float isum[MT];
  __shared__ int   ti[MT][2];

  const int t  = threadIdx.x;
  const int w  = t >> 6;       // wave 0..3 -> cols [w*32, w*32+32)
  const int l  = t & 63;
  const int q  = l >> 4;
  const int cl = l & 15;
  const int t0 = blockIdx.x * MT;

  // x staging: thread covers token (t>>2), k in [(t&3)*8, +8)
  const int stok = t >> 2;
  const int skof = (t & 3) * 8;
  const float* xrow = x + (size_t)(t0 + stok) * DD + skof;

  floatx4 acc[4][2];
#pragma unroll
  for (int mt = 0; mt < 4; ++mt)
#pragma unroll
    for (int nt = 0; nt < 2; ++nt) acc[mt][nt] = (floatx4)0.f;

  const half8* wfp = (const half8*)wf;
  half8 Bc[2][2], Bn[2][2];

  // ---- preamble: chunk 0 ----
  {
    float4 a = *reinterpret_cast<const float4*>(xrow);
    float4 b = *reinterpret_cast<const float4*>(xrow + 4);
    float v[8] = {a.x, a.y, a.z, a.w, b.x, b.y, b.z, b.w};
    half8 hi, lo;
#pragma unroll
    for (int j = 0; j < 8; ++j) {
      _Float16 h = (_Float16)v[j];
      hi[j] = h;
      lo[j] = (_Float16)(v[j] - (float)h);
    }
    *reinterpret_cast<half8*>(&xs[0][0][stok * LDA + skof]) = hi;
    *reinterpret_cast<half8*>(&xs[0][1][stok * LDA + skof]) = lo;
#pragma unroll
    for (int nt = 0; nt < 2; ++nt) {
      int ct = w * 2 + nt;
#pragma unroll
      for (int s = 0; s < 2; ++s)
        Bc[nt][s] = wfp[((size_t)(ct * 64 + 0) * 2 + s) * 64 + l];
    }
  }

  for (int kc = 0; kc < NKC; ++kc) {
    const int cur = kc & 1;
    // prefetch x chunk kc+1
    float4 pa, pb;
    const bool more = (kc < NKC - 1);
    if (more) {
      pa = *reinterpret_cast<const float4*>(xrow + (kc + 1) * BKC);
      pb = *reinterpret_cast<const float4*>(xrow + (kc + 1) * BKC + 4);
#pragma unroll
      for (int nt = 0; nt < 2; ++nt) {
        int ct = w * 2 + nt;
#pragma unroll
        for (int s = 0; s < 2; ++s)
          Bn[nt][s] = wfp[((size_t)(ct * 64 + kc + 1) * 2 + s) * 64 + l];
      }
    }
    __syncthreads();   // LDS[cur] ready

    // A fragments: 4 m-tiles x {hi,lo}
    half8 Ah[4], Al[4];
#pragma unroll
    for (int mt = 0; mt < 4; ++mt) {
      Ah[mt] = *reinterpret_cast<const half8*>(&xs[cur][0][(mt * 16 + cl) * LDA + q * 8]);
      Al[mt] = *reinterpret_cast<const half8*>(&xs[cur][1][(mt * 16 + cl) * LDA + q * 8]);
    }
    // 3-term split-2 product: hi*hi, hi*lo, lo*hi  (24 MFMA)
#pragma unroll
    for (int mt = 0; mt < 4; ++mt)
#pragma unroll
      for (int nt = 0; nt < 2; ++nt)
        acc[mt][nt] = __builtin_amdgcn_mfma_f32_16x16x32_f16(Ah[mt], Bc[nt][0], acc[mt][nt], 0, 0, 0);
#pragma unroll
    for (int mt = 0; mt < 4; ++mt)
#pragma unroll
      for (int nt = 0; nt < 2; ++nt)
        acc[mt][nt] = __builtin_amdgcn_mfma_f32_16x16x32_f16(Ah[mt], Bc[nt][1], acc[mt][nt], 0, 0, 0);
#pragma unroll
    for (int mt = 0; mt < 4; ++mt)
#pragma unroll
      for (int nt = 0; nt < 2; ++nt)
        acc[mt][nt] = __builtin_amdgcn_mfma_f32_16x16x32_f16(Al[mt], Bc[nt][0], acc[mt][nt], 0, 0, 0);

    if (more) {
      float v[8] = {pa.x, pa.y, pa.z, pa.w, pb.x, pb.y, pb.z, pb.w};
      half8 hi, lo;
#pragma unroll
      for (int j = 0; j < 8; ++j) {
        _Float16 h = (_Float16)v[j];
        hi[j] = h;
        lo[j] = (_Float16)(v[j] - (float)h);
      }
      *reinterpret_cast<half8*>(&xs[cur ^ 1][0][stok * LDA + skof]) = hi;
      *reinterpret_cast<half8*>(&xs[cur ^ 1][1][stok * LDA + skof]) = lo;
#pragma unroll
      for (int nt = 0; nt < 2; ++nt)
#pragma unroll
        for (int s = 0; s < 2; ++s) Bc[nt][s] = Bn[nt][s];
    }
  }

  // ---- epilogue ----
  // C/D layout: col = lane&15, row(token) = (lane>>4)*4 + reg
#pragma unroll
  for (int mt = 0; mt < 4; ++mt)
#pragma unroll
    for (int nt = 0; nt < 2; ++nt)
#pragma unroll
      for (int r = 0; r < 4; ++r)
        Lb[mt * 16 + q * 4 + r][w * 32 + nt * 16 + cl] = acc[mt][nt][r];

  if (t < EE) Bgs[t] = bg[t];
#pragma unroll
  for (int i = 0; i < 16; ++i) Sb[t + 256 * i] = 0.f;
  // stage raw_noise tile (coalesced)
#pragma unroll
  for (int i = 0; i < 16; ++i) {
    int idx = t + 256 * i;
    Rb[idx >> 6][idx & 63] = rn[(size_t)t0 * EE + idx];
  }
  __syncthreads();

  if (t < MT) {
    float v1 = -1e30f, v2 = -1e30f;
    int   i1 = 0, i2 = 0;
    float s = 0.f;
    for (int e = 0; e < EE; ++e) {
      float g  = Lb[t][e] + Bgs[e];
      float h  = Lb[t][EE + e];
      float sp = (h > 20.f) ? h : log1pf(expf(h));
      float v  = g + Rb[t][e] * (sp + 0.01f);
      float ev = expf(v);
      s += ev;
      Pb[t][e] = ev;
      if (v > v1)      { v2 = v1; i2 = i1; v1 = v; i1 = e; }
      else if (v > v2) { v2 = v;  i2 = e; }
    }
    isum[t] = 1.f / s;
    ti[t][0] = i1; ti[t][1] = i2;
    float e2 = expf(v2 - v1);
    float dn = 1.f + e2;
    Sb[t * EE + i1] = 1.f / dn;
    Sb[t * EE + i2] = e2 / dn;
  }
  __syncthreads();

  // coalesced sparse write: 64 tokens x 64 experts
#pragma unroll
  for (int i = 0; i < 16; ++i)
    out[(size_t)t0 * EE + t + 256 * i] = Sb[t + 256 * i];

  // aux partials
  if (t < EE) {
    float s = 0.f;
    int   c = 0;
#pragma unroll
    for (int m = 0; m < MT; ++m) {
      s += Pb[m][t] * isum[m];
      c += (ti[m][0] == t) + (ti[m][1] == t);
    }
    atomicAdd(&psum_g[t], s);
    atomicAdd(&cnt_g[t], (float)c);
  }
}

__global__ void aux_kernel(const float* __restrict__ cnt_g,
                           const float* __restrict__ psum_g,
                           float* __restrict__ out) {
  int e = threadIdx.x;  // 64 lanes, one wave
  float v = cnt_g[e] * psum_g[e];
#pragma unroll
  for (int o = 32; o > 0; o >>= 1) v += __shfl_down(v, o);
  if (e == 0)
    out[(size_t)TOK * EE] = v * ((float)EE / ((float)TOK * (float)TOK));
}

extern "C" void kernel_launch(void* const* d_in, const int* in_sizes, int n_in,
                              void* d_out, int out_size, void* d_ws, size_t ws_size,
                              hipStream_t stream) {
  const float* x  = (const float*)d_in[0];
  const float* rn = (const float*)d_in[1];
  const float* Wg = (const float*)d_in[2];
  const float* bg = (const float*)d_in[3];
  const float* Wn = (const float*)d_in[4];
  float* out    = (float*)d_out;
  float* cnt_g  = (float*)d_ws;
  float* psum_g = cnt_g + EE;
  _Float16* wf  = (_Float16*)((float*)d_ws + 128);   // 1 MiB of pre-split W frags

  hipMemsetAsync(d_ws, 0, 2 * EE * sizeof(float), stream);
  build_wf<<<128, 256, 0, stream>>>(Wg, Wn, wf);
  gating_kernel<<<TOK / MT, 256, 0, stream>>>(x, rn, wf, bg, out, cnt_g, psum_g);
  aux_kernel<<<1, 64, 0, stream>>>(cnt_g, psum_g, out);
}

// Round 3
// 240.591 us; speedup vs baseline: 1.8685x; 1.0366x over previous
//
#include <hip/hip_runtime.h>
#include <math.h>

#define TOK 16384
#define DD  2048
#define EE  64
#define MT  32           // tokens per block -> grid 512 = 2 blocks/CU
#define BKC 32           // k per chunk
#define NKC 64           // DD / BKC
#define LDA 40           // halves per token row in LDS (80B stride, <=2-way conflicts)

typedef _Float16 half4v __attribute__((ext_vector_type(4)));
typedef _Float16 half8  __attribute__((ext_vector_type(8)));
typedef float    floatx4 __attribute__((ext_vector_type(4)));

// ---- W pre-split: f32 -> (hi,lo) f16, frag-major layout (same as R2) ----
// wf frag index ((ct*64+kc)*2+s)*64+lane, 8 halves each.
// ct 0..3 = gate col-tiles (cols ct*16+cl), ct 4..7 = noise col-tiles.
__global__ void build_wf(const float* __restrict__ Wg, const float* __restrict__ Wn,
                         _Float16* __restrict__ wf) {
  int tid  = blockIdx.x * 256 + threadIdx.x;   // 32768 threads
  int lane = tid & 63;
  int kc   = (tid >> 6) & 63;
  int ct   = tid >> 12;                        // 0..7
  int col  = (ct & 3) * 16 + (lane & 15);
  int k    = kc * 32 + (lane >> 4) * 8;
  const float* W = (ct < 4) ? Wg : Wn;
  const float* src = W + (size_t)col * DD + k;
  float4 a = *reinterpret_cast<const float4*>(src);
  float4 b = *reinterpret_cast<const float4*>(src + 4);
  float v[8] = {a.x, a.y, a.z, a.w, b.x, b.y, b.z, b.w};
  half8 hi, lo;
#pragma unroll
  for (int j = 0; j < 8; ++j) {
    _Float16 h = (_Float16)v[j];
    hi[j] = h;
    lo[j] = (_Float16)(v[j] - (float)h);
  }
  size_t base = (((size_t)(ct * 64 + kc) * 2 + 0) * 64 + lane) * 8;
  *reinterpret_cast<half8*>(wf + base)       = hi;
  *reinterpret_cast<half8*>(wf + base + 512) = lo;
}

// LDS plan (union via phase barrier):
//   K-phase : xs[2][2][MT*LDA] halves = 10240 B at offset 0
//   E-phase : Vb[32][66] f32 @0 (8448) | Eb[32][66] @8448 | isum[32] @16896
//             ti[32][2] @17024 | tp[32][2] @17280   -> total 17536 B
__global__ __launch_bounds__(256, 2)
void gating_kernel(const float* __restrict__ x, const float* __restrict__ rn,
                   const _Float16* __restrict__ wf, const float* __restrict__ bg,
                   float* __restrict__ out,
                   float* __restrict__ cnt_g, float* __restrict__ psum_g) {
  __shared__ char smem[17536];
  _Float16* xs  = (_Float16*)smem;
  float*    Vb  = (float*)smem;
  float*    Eb  = (float*)(smem + 8448);
  float*    isum= (float*)(smem + 16896);
  int*      ti  = (int*)(smem + 17024);
  float*    tp  = (float*)(smem + 17280);

  const int t  = threadIdx.x;
  const int w  = t >> 6;       // wave 0..3 -> expert cols [w*16, w*16+16)
  const int l  = t & 63;
  const int q  = l >> 4;
  const int cl = l & 15;
  const int c  = w * 16 + cl;  // this lane's expert column (gate AND noise)
  const int t0 = blockIdx.x * MT;

  // x staging: thread covers token t>>3, k-offset (t&7)*4 (one float4/chunk)
  const int stok = t >> 3;
  const int skof = (t & 7) * 4;
  const float* xrow = x + (size_t)(t0 + stok) * DD + skof;

  // preload epilogue operands (independent of K-loop; hides their latency)
  const float bgv = bg[c];
  float rnv[2][4];
#pragma unroll
  for (int mt = 0; mt < 2; ++mt)
#pragma unroll
    for (int r = 0; r < 4; ++r)
      rnv[mt][r] = rn[(size_t)(t0 + mt * 16 + q * 4 + r) * EE + c];

  floatx4 acc[2][2];
#pragma unroll
  for (int mt = 0; mt < 2; ++mt)
#pragma unroll
    for (int nt = 0; nt < 2; ++nt) acc[mt][nt] = (floatx4)0.f;

  const half8* wfp = (const half8*)wf;
  half8 Bc[2][2], Bn[2][2];

  // ---- preamble: chunk 0 ----
  {
    float4 a = *reinterpret_cast<const float4*>(xrow);
    float v[4] = {a.x, a.y, a.z, a.w};
    half4v hi, lo;
#pragma unroll
    for (int j = 0; j < 4; ++j) {
      _Float16 h = (_Float16)v[j];
      hi[j] = h;
      lo[j] = (_Float16)(v[j] - (float)h);
    }
    *reinterpret_cast<half4v*>(&xs[(0 * 2 + 0) * MT * LDA + stok * LDA + skof]) = hi;
    *reinterpret_cast<half4v*>(&xs[(0 * 2 + 1) * MT * LDA + stok * LDA + skof]) = lo;
#pragma unroll
    for (int nt = 0; nt < 2; ++nt) {
      const int ct = w + nt * 4;   // nt=0 gate, nt=1 noise -> same cols
#pragma unroll
      for (int s = 0; s < 2; ++s)
        Bc[nt][s] = wfp[((size_t)(ct * 64 + 0) * 2 + s) * 64 + l];
    }
  }

  for (int kc = 0; kc < NKC; ++kc) {
    const int cur = kc & 1;
    const bool more = (kc < NKC - 1);
    float4 pa;
    if (more) {
      pa = *reinterpret_cast<const float4*>(xrow + (kc + 1) * BKC);
#pragma unroll
      for (int nt = 0; nt < 2; ++nt) {
        const int ct = w + nt * 4;
#pragma unroll
        for (int s = 0; s < 2; ++s)
          Bn[nt][s] = wfp[((size_t)(ct * 64 + kc + 1) * 2 + s) * 64 + l];
      }
    }
    __syncthreads();   // xs[cur] ready; xs[cur^1] reads from prev iter done

    half8 Ah[2], Al[2];
#pragma unroll
    for (int mt = 0; mt < 2; ++mt) {
      Ah[mt] = *reinterpret_cast<const half8*>(
          &xs[(cur * 2 + 0) * MT * LDA + (mt * 16 + cl) * LDA + q * 8]);
      Al[mt] = *reinterpret_cast<const half8*>(
          &xs[(cur * 2 + 1) * MT * LDA + (mt * 16 + cl) * LDA + q * 8]);
    }
    // split-2 product: hi*hi + hi*lo + lo*hi  (12 MFMA)
#pragma unroll
    for (int mt = 0; mt < 2; ++mt)
#pragma unroll
      for (int nt = 0; nt < 2; ++nt)
        acc[mt][nt] = __builtin_amdgcn_mfma_f32_16x16x32_f16(Ah[mt], Bc[nt][0], acc[mt][nt], 0, 0, 0);
#pragma unroll
    for (int mt = 0; mt < 2; ++mt)
#pragma unroll
      for (int nt = 0; nt < 2; ++nt)
        acc[mt][nt] = __builtin_amdgcn_mfma_f32_16x16x32_f16(Ah[mt], Bc[nt][1], acc[mt][nt], 0, 0, 0);
#pragma unroll
    for (int mt = 0; mt < 2; ++mt)
#pragma unroll
      for (int nt = 0; nt < 2; ++nt)
        acc[mt][nt] = __builtin_amdgcn_mfma_f32_16x16x32_f16(Al[mt], Bc[nt][0], acc[mt][nt], 0, 0, 0);

    if (more) {
      float v[4] = {pa.x, pa.y, pa.z, pa.w};
      half4v hi, lo;
#pragma unroll
      for (int j = 0; j < 4; ++j) {
        _Float16 h = (_Float16)v[j];
        hi[j] = h;
        lo[j] = (_Float16)(v[j] - (float)h);
      }
      *reinterpret_cast<half4v*>(&xs[((cur ^ 1) * 2 + 0) * MT * LDA + stok * LDA + skof]) = hi;
      *reinterpret_cast<half4v*>(&xs[((cur ^ 1) * 2 + 1) * MT * LDA + stok * LDA + skof]) = lo;
#pragma unroll
      for (int nt = 0; nt < 2; ++nt)
#pragma unroll
        for (int s = 0; s < 2; ++s) Bc[nt][s] = Bn[nt][s];
    }
  }

  __syncthreads();   // all xs reads done; smem becomes Vb/Eb

  // ---- lane pass: noisy logit + exp, all in-register (gate/noise same lane) ----
#pragma unroll
  for (int mt = 0; mt < 2; ++mt)
#pragma unroll
    for (int r = 0; r < 4; ++r) {
      const int tk = mt * 16 + q * 4 + r;     // C/D layout: row = q*4+r
      float g  = acc[mt][0][r] + bgv;
      float h  = acc[mt][1][r];
      float sp = (h > 20.f) ? h : log1pf(expf(h));
      float v  = g + rnv[mt][r] * (sp + 0.01f);
      Vb[tk * 66 + c] = v;
      Eb[tk * 66 + c] = expf(v);
    }
  __syncthreads();

  // ---- per-token top-2 + softmax denom (32 threads) ----
  if (t < MT) {
    float v1 = -1e30f, v2 = -1e30f;
    int   i1 = 0, i2 = 0;
    float s = 0.f;
    for (int e = 0; e < EE; ++e) {
      float v = Vb[t * 66 + e];
      s += Eb[t * 66 + e];
      if (v > v1)      { v2 = v1; i2 = i1; v1 = v; i1 = e; }
      else if (v > v2) { v2 = v;  i2 = e; }
    }
    isum[t] = 1.f / s;
    ti[t * 2 + 0] = i1; ti[t * 2 + 1] = i2;
    float e2 = expf(v2 - v1);
    float dn = 1.f + e2;
    tp[t * 2 + 0] = 1.f / dn;
    tp[t * 2 + 1] = e2 / dn;
  }
  __syncthreads();

  // ---- sparse out: patched zero-fill, one coalesced pass (8 floats/thread) ----
  {
    const int m  = t >> 3;
    const int c0 = (t & 7) * 8;
    const int i1 = ti[m * 2 + 0], i2 = ti[m * 2 + 1];
    const float p1 = tp[m * 2 + 0], p2 = tp[m * 2 + 1];
    float o[8];
#pragma unroll
    for (int j = 0; j < 8; ++j) {
      const int col = c0 + j;
      o[j] = (col == i1) ? p1 : ((col == i2) ? p2 : 0.f);
    }
    float* dst = out + (size_t)(t0 + m) * EE + c0;
    *reinterpret_cast<float4*>(dst)     = make_float4(o[0], o[1], o[2], o[3]);
    *reinterpret_cast<float4*>(dst + 4) = make_float4(o[4], o[5], o[6], o[7]);
  }

  // ---- aux partials: per-expert psum & count ----
  if (t < EE) {
    float s = 0.f;
    int   cn = 0;
#pragma unroll
    for (int m = 0; m < MT; ++m) {
      s  += Eb[m * 66 + t] * isum[m];
      cn += (ti[m * 2 + 0] == t) + (ti[m * 2 + 1] == t);
    }
    atomicAdd(&psum_g[t], s);
    atomicAdd(&cnt_g[t], (float)cn);
  }
}

__global__ void aux_kernel(const float* __restrict__ cnt_g,
                           const float* __restrict__ psum_g,
                           float* __restrict__ out) {
  int e = threadIdx.x;  // 64 lanes, one wave
  float v = cnt_g[e] * psum_g[e];
#pragma unroll
  for (int o = 32; o > 0; o >>= 1) v += __shfl_down(v, o);
  if (e == 0)
    out[(size_t)TOK * EE] = v * ((float)EE / ((float)TOK * (float)TOK));
}

extern "C" void kernel_launch(void* const* d_in, const int* in_sizes, int n_in,
                              void* d_out, int out_size, void* d_ws, size_t ws_size,
                              hipStream_t stream) {
  const float* x  = (const float*)d_in[0];
  const float* rn = (const float*)d_in[1];
  const float* Wg = (const float*)d_in[2];
  const float* bg = (const float*)d_in[3];
  const float* Wn = (const float*)d_in[4];
  float* out    = (float*)d_out;
  float* cnt_g  = (float*)d_ws;
  float* psum_g = cnt_g + EE;
  _Float16* wf  = (_Float16*)((float*)d_ws + 128);   // 1 MiB of pre-split W frags

  hipMemsetAsync(d_ws, 0, 2 * EE * sizeof(float), stream);
  build_wf<<<128, 256, 0, stream>>>(Wg, Wn, wf);
  gating_kernel<<<TOK / MT, 256, 0, stream>>>(x, rn, wf, bg, out, cnt_g, psum_g);
  aux_kernel<<<1, 64, 0, stream>>>(cnt_g, psum_g, out);
}

// Round 4
// 235.692 us; speedup vs baseline: 1.9073x; 1.0208x over previous
//
#include <hip/hip_runtime.h>
#include <math.h>

#define TOK 16384
#define DD  2048
#define EE  64
#define MT  32           // tokens per block
#define BK  32           // k per chunk
#define NKC 32           // chunks per K-group (each group covers 1024)
#define LDA 40           // halves per token row in LDS (80B stride, <=2-way conflicts)

typedef _Float16 half4v __attribute__((ext_vector_type(4)));
typedef _Float16 half8  __attribute__((ext_vector_type(8)));
typedef float    floatx4 __attribute__((ext_vector_type(4)));

// ---- W pre-split: f32 -> (hi,lo) f16, frag-major layout ----
// wf frag index ((ct*64+kc)*2+s)*64+lane, 8 halves each.
// ct 0..3 = gate col-tiles (cols ct*16+cl), ct 4..7 = noise col-tiles.
__global__ void build_wf(const float* __restrict__ Wg, const float* __restrict__ Wn,
                         _Float16* __restrict__ wf) {
  int tid  = blockIdx.x * 256 + threadIdx.x;   // 32768 threads
  int lane = tid & 63;
  int kc   = (tid >> 6) & 63;
  int ct   = tid >> 12;                        // 0..7
  int col  = (ct & 3) * 16 + (lane & 15);
  int k    = kc * 32 + (lane >> 4) * 8;
  const float* W = (ct < 4) ? Wg : Wn;
  const float* src = W + (size_t)col * DD + k;
  float4 a = *reinterpret_cast<const float4*>(src);
  float4 b = *reinterpret_cast<const float4*>(src + 4);
  float v[8] = {a.x, a.y, a.z, a.w, b.x, b.y, b.z, b.w};
  half8 hi, lo;
#pragma unroll
  for (int j = 0; j < 8; ++j) {
    _Float16 h = (_Float16)v[j];
    hi[j] = h;
    lo[j] = (_Float16)(v[j] - (float)h);
  }
  size_t base = (((size_t)(ct * 64 + kc) * 2 + 0) * 64 + lane) * 8;
  *reinterpret_cast<half8*>(wf + base)       = hi;
  *reinterpret_cast<half8*>(wf + base + 512) = lo;
}

// LDS plan:
//   K-phase : xs[g][buf][split][32*LDA] halves = 20480 B @0
//   E-phase : Pacc 64x64 f32 @0 (16384) | Vb[32][66] @16384 | Eb[32][66] @24832
//             isum @33280 | ti @33408 | tp @33664  -> 33920 B total
__global__ __launch_bounds__(512, 4)
void gating_kernel(const float* __restrict__ x, const float* __restrict__ rn,
                   const _Float16* __restrict__ wf, const float* __restrict__ bg,
                   float* __restrict__ out,
                   float* __restrict__ cnt_g, float* __restrict__ psum_g) {
  __shared__ char smem[33920];
  _Float16* xs   = (_Float16*)smem;
  float*    Pacc = (float*)smem;
  float*    Vb   = (float*)(smem + 16384);
  float*    Eb   = (float*)(smem + 24832);
  float*    isum = (float*)(smem + 33280);
  int*      ti   = (int*)(smem + 33408);
  float*    tp   = (float*)(smem + 33664);

  const int t  = threadIdx.x;
  const int g  = t >> 8;        // K-group: 0 -> K[0,1024), 1 -> K[1024,2048)
  const int tg = t & 255;
  const int w4 = tg >> 6;       // ct-pair 0..3 -> expert cols [w4*16, +16)
  const int l  = t & 63;
  const int q  = l >> 4;
  const int cl = l & 15;
  const int c  = w4 * 16 + cl;
  const int t0 = blockIdx.x * MT;

  // x staging (per group): thread covers token tg>>3, k-offset (tg&7)*4
  const int stok = tg >> 3;
  const int skof = (tg & 7) * 4;
  const float* xrow = x + (size_t)(t0 + stok) * DD + g * (NKC * BK) + skof;

  // epilogue operands (group 0 only)
  float bgv = 0.f;
  float rnv[2][4] = {{0.f,0.f,0.f,0.f},{0.f,0.f,0.f,0.f}};
  if (g == 0) {
    bgv = bg[c];
#pragma unroll
    for (int mt = 0; mt < 2; ++mt)
#pragma unroll
      for (int r = 0; r < 4; ++r)
        rnv[mt][r] = rn[(size_t)(t0 + mt * 16 + q * 4 + r) * EE + c];
  }

  floatx4 acc[2][2];
#pragma unroll
  for (int mt = 0; mt < 2; ++mt)
#pragma unroll
    for (int nt = 0; nt < 2; ++nt) acc[mt][nt] = (floatx4)0.f;

  const half8* wfp = (const half8*)wf;
  half8 B[2][2][2];   // [parity][nt][s]

  // ---- preamble: chunk 0 of this group ----
  {
    float4 a = *reinterpret_cast<const float4*>(xrow);
    float v[4] = {a.x, a.y, a.z, a.w};
    half4v hi, lo;
#pragma unroll
    for (int j = 0; j < 4; ++j) {
      _Float16 h = (_Float16)v[j];
      hi[j] = h;
      lo[j] = (_Float16)(v[j] - (float)h);
    }
    *reinterpret_cast<half4v*>(&xs[((g * 2 + 0) * 2 + 0) * (MT * LDA) + stok * LDA + skof]) = hi;
    *reinterpret_cast<half4v*>(&xs[((g * 2 + 0) * 2 + 1) * (MT * LDA) + stok * LDA + skof]) = lo;
#pragma unroll
    for (int nt = 0; nt < 2; ++nt) {
      const int ct = w4 + nt * 4;
#pragma unroll
      for (int s = 0; s < 2; ++s)
        B[0][nt][s] = wfp[((size_t)(ct * 64 + g * NKC) * 2 + s) * 64 + l];
    }
  }

#pragma unroll 4
  for (int kc = 0; kc < NKC; ++kc) {
    const int cur = kc & 1;
    const bool more = (kc < NKC - 1);
    float4 pa;
    if (more) {
      pa = *reinterpret_cast<const float4*>(xrow + (kc + 1) * BK);
#pragma unroll
      for (int nt = 0; nt < 2; ++nt) {
        const int ct = w4 + nt * 4;
#pragma unroll
        for (int s = 0; s < 2; ++s)
          B[cur ^ 1][nt][s] = wfp[((size_t)(ct * 64 + g * NKC + kc + 1) * 2 + s) * 64 + l];
      }
    }
    __syncthreads();   // xs[g][cur] ready

    half8 Ah[2], Al[2];
#pragma unroll
    for (int mt = 0; mt < 2; ++mt) {
      Ah[mt] = *reinterpret_cast<const half8*>(
          &xs[((g * 2 + cur) * 2 + 0) * (MT * LDA) + (mt * 16 + cl) * LDA + q * 8]);
      Al[mt] = *reinterpret_cast<const half8*>(
          &xs[((g * 2 + cur) * 2 + 1) * (MT * LDA) + (mt * 16 + cl) * LDA + q * 8]);
    }
    // split-2 product: hi*hi + hi*lo + lo*hi  (12 MFMA)
#pragma unroll
    for (int mt = 0; mt < 2; ++mt)
#pragma unroll
      for (int nt = 0; nt < 2; ++nt)
        acc[mt][nt] = __builtin_amdgcn_mfma_f32_16x16x32_f16(Ah[mt], B[cur][nt][0], acc[mt][nt], 0, 0, 0);
#pragma unroll
    for (int mt = 0; mt < 2; ++mt)
#pragma unroll
      for (int nt = 0; nt < 2; ++nt)
        acc[mt][nt] = __builtin_amdgcn_mfma_f32_16x16x32_f16(Ah[mt], B[cur][nt][1], acc[mt][nt], 0, 0, 0);
#pragma unroll
    for (int mt = 0; mt < 2; ++mt)
#pragma unroll
      for (int nt = 0; nt < 2; ++nt)
        acc[mt][nt] = __builtin_amdgcn_mfma_f32_16x16x32_f16(Al[mt], B[cur][nt][0], acc[mt][nt], 0, 0, 0);

    if (more) {
      float v[4] = {pa.x, pa.y, pa.z, pa.w};
      half4v hi, lo;
#pragma unroll
      for (int j = 0; j < 4; ++j) {
        _Float16 h = (_Float16)v[j];
        hi[j] = h;
        lo[j] = (_Float16)(v[j] - (float)h);
      }
      *reinterpret_cast<half4v*>(&xs[((g * 2 + (cur ^ 1)) * 2 + 0) * (MT * LDA) + stok * LDA + skof]) = hi;
      *reinterpret_cast<half4v*>(&xs[((g * 2 + (cur ^ 1)) * 2 + 1) * (MT * LDA) + stok * LDA + skof]) = lo;
    }
  }

  __syncthreads();   // xs dead; smem becomes Pacc/Vb/Eb

  // ---- split-K merge: group 1 -> LDS, group 0 adds ----
  if (g == 1) {
#pragma unroll
    for (int mt = 0; mt < 2; ++mt)
#pragma unroll
      for (int nt = 0; nt < 2; ++nt)
#pragma unroll
        for (int r = 0; r < 4; ++r)
          Pacc[((((w4 * 2 + mt) * 2 + nt) * 4) + r) * 64 + l] = acc[mt][nt][r];
  }
  __syncthreads();

  if (g == 0) {
#pragma unroll
    for (int mt = 0; mt < 2; ++mt)
#pragma unroll
      for (int nt = 0; nt < 2; ++nt)
#pragma unroll
        for (int r = 0; r < 4; ++r)
          acc[mt][nt][r] += Pacc[((((w4 * 2 + mt) * 2 + nt) * 4) + r) * 64 + l];

    // lane pass: noisy logit + exp, in-register (gate/noise same lane)
#pragma unroll
    for (int mt = 0; mt < 2; ++mt)
#pragma unroll
      for (int r = 0; r < 4; ++r) {
        const int tk = mt * 16 + q * 4 + r;   // C/D layout: row = q*4+r
        float gt = acc[mt][0][r] + bgv;
        float h  = acc[mt][1][r];
        float sp = (h > 20.f) ? h : log1pf(expf(h));
        float v  = gt + rnv[mt][r] * (sp + 0.01f);
        Vb[tk * 66 + c] = v;
        Eb[tk * 66 + c] = expf(v);
      }
  }
  __syncthreads();

  // ---- per-token top-2 + softmax denom (32 threads) ----
  if (t < MT) {
    float v1 = -1e30f, v2 = -1e30f;
    int   i1 = 0, i2 = 0;
    float s = 0.f;
    for (int e = 0; e < EE; ++e) {
      float v = Vb[t * 66 + e];
      s += Eb[t * 66 + e];
      if (v > v1)      { v2 = v1; i2 = i1; v1 = v; i1 = e; }
      else if (v > v2) { v2 = v;  i2 = e; }
    }
    isum[t] = 1.f / s;
    ti[t * 2 + 0] = i1; ti[t * 2 + 1] = i2;
    float e2 = expf(v2 - v1);
    float dn = 1.f + e2;
    tp[t * 2 + 0] = 1.f / dn;
    tp[t * 2 + 1] = e2 / dn;
  }
  __syncthreads();

  // ---- sparse out: patched zero-fill, all 512 threads, one float4 each ----
  {
    const int m  = t >> 4;
    const int c0 = (t & 15) * 4;
    const int i1 = ti[m * 2 + 0], i2 = ti[m * 2 + 1];
    const float p1 = tp[m * 2 + 0], p2 = tp[m * 2 + 1];
    float o[4];
#pragma unroll
    for (int j = 0; j < 4; ++j) {
      const int col = c0 + j;
      o[j] = (col == i1) ? p1 : ((col == i2) ? p2 : 0.f);
    }
    *reinterpret_cast<float4*>(out + (size_t)(t0 + m) * EE + c0) =
        make_float4(o[0], o[1], o[2], o[3]);
  }

  // ---- aux partials: per-expert psum & count ----
  if (t < EE) {
    float s = 0.f;
    int   cn = 0;
#pragma unroll
    for (int m = 0; m < MT; ++m) {
      s  += Eb[m * 66 + t] * isum[m];
      cn += (ti[m * 2 + 0] == t) + (ti[m * 2 + 1] == t);
    }
    atomicAdd(&psum_g[t], s);
    atomicAdd(&cnt_g[t], (float)cn);
  }
}

__global__ void aux_kernel(const float* __restrict__ cnt_g,
                           const float* __restrict__ psum_g,
                           float* __restrict__ out) {
  int e = threadIdx.x;  // 64 lanes, one wave
  float v = cnt_g[e] * psum_g[e];
#pragma unroll
  for (int o = 32; o > 0; o >>= 1) v += __shfl_down(v, o);
  if (e == 0)
    out[(size_t)TOK * EE] = v * ((float)EE / ((float)TOK * (float)TOK));
}

extern "C" void kernel_launch(void* const* d_in, const int* in_sizes, int n_in,
                              void* d_out, int out_size, void* d_ws, size_t ws_size,
                              hipStream_t stream) {
  const float* x  = (const float*)d_in[0];
  const float* rn = (const float*)d_in[1];
  const float* Wg = (const float*)d_in[2];
  const float* bg = (const float*)d_in[3];
  const float* Wn = (const float*)d_in[4];
  float* out    = (float*)d_out;
  float* cnt_g  = (float*)d_ws;
  float* psum_g = cnt_g + EE;
  _Float16* wf  = (_Float16*)((float*)d_ws + 128);   // 1 MiB of pre-split W frags

  hipMemsetAsync(d_ws, 0, 2 * EE * sizeof(float), stream);
  build_wf<<<128, 256, 0, stream>>>(Wg, Wn, wf);
  gating_kernel<<<TOK / MT, 512, 0, stream>>>(x, rn, wf, bg, out, cnt_g, psum_g);
  aux_kernel<<<1, 64, 0, stream>>>(cnt_g, psum_g, out);
}